// Round 1
// baseline (251.856 us; speedup 1.0000x reference)
//
#include <hip/hip_runtime.h>
#include <hip/hip_bf16.h>
#include <stdint.h>

// Correlation (FlowNet-style), md=4, K=9, 81 displacement planes.
// x,y: [B=8, C=256, H=96, W=192] fp32 -> out: [B, 81, H, W] fp32.
//
// Formulation: for each (h, di), out[w][dj] is the 9-wide band of
// G = X^T * Y  (X = x-row tile 16w x Kc, Y = y-row window 24s x Kc),
// computed with v_mfma_f32_16x16x16_bf16 (_1k builtin), fp32 accum.
// Band: dj = t*16 + n - m  (t = N-tile 0/1), keep 0 <= dj <= 8.

using f32x4 = __attribute__((ext_vector_type(4))) float;
using s16x4 = __attribute__((ext_vector_type(4))) short;

#define C_DIM 256
#define H_DIM 96
#define W_DIM 192
#define MD 4
#define KD 9
#define CHUNK 32            // channels staged per LDS chunk
#define HR 4                // h rows per block (one per wave)
#define ROWS 16             // 12 y rows (h0-4 .. h0+7) + 4 x rows
#define SW 24               // staged s-window: w0-4 .. w0+19
#define SPAD 28             // padded row stride in dwords (112B, 16B-aligned;
                            // (hi*4)*28*4 = 448B == 16*hi mod 128B -> 2-way banks = free)
#define TILE_DW (ROWS * CHUNK * SPAD)   // 14336 dwords = 56 KiB
#define WTILES (W_DIM / 16)             // 12
#define HQ (H_DIM / HR)                 // 24

__device__ __forceinline__ short bf16bits(float f) {
  __bf16 h = (__bf16)f;                 // RNE convert
  short s;
  __builtin_memcpy(&s, &h, 2);
  return s;
}

__global__ __launch_bounds__(256, 2)
void corr_mfma(const float* __restrict__ xg, const float* __restrict__ yg,
               float* __restrict__ outg) {
  __shared__ float lds[TILE_DW + 4];    // +4: tile1 fragment reads may run 3 dwords
                                        // past the last padded row (values unused)

  const int bid = blockIdx.x;
  const int wt = bid % WTILES;
  const int hq = (bid / WTILES) % HQ;
  const int b  = bid / (WTILES * HQ);
  const int w0 = wt * 16;
  const int h0 = hq * HR;

  const int tid  = threadIdx.x;
  const int lane = tid & 63;
  const int wv   = tid >> 6;            // wave id 0..3 -> output row h0+wv
  const int hi   = lane >> 4;           // 0..3
  const int lm   = lane & 15;           // MFMA m/n lane coordinate

  f32x4 acc[KD][2];
#pragma unroll
  for (int di = 0; di < KD; ++di) {
    acc[di][0] = f32x4{0.f, 0.f, 0.f, 0.f};
    acc[di][1] = f32x4{0.f, 0.f, 0.f, 0.f};
  }

  for (int c0 = 0; c0 < C_DIM; c0 += CHUNK) {
    // ---- issue global loads: 3072 16B-quads, 12 per thread.
    // qid -> (r row 0..15, c channel 0..31, q s-quad 0..5). Rows 0..11 are y
    // rows h0+r-4 (zero-filled OOB = the reference's zero padding); rows
    // 12..15 are x rows h0+(r-12). Loads issue before the barrier so HBM
    // latency overlaps the other waves' previous compute phase.
    float4 v[12];
#pragma unroll
    for (int i = 0; i < 12; ++i) {
      const int qid = i * 256 + tid;
      const int q = qid % 6;
      const int c = (qid / 6) % CHUNK;
      const int r = qid / (6 * CHUNK);
      const int sg = w0 - MD + q * 4;   // 4-aligned -> OOB is whole-quad only
      float4 val = make_float4(0.f, 0.f, 0.f, 0.f);
      if (r < 12) {
        const int hg = h0 + r - MD;
        if (hg >= 0 && hg < H_DIM && sg >= 0 && sg < W_DIM)
          val = *(const float4*)&yg[((b * C_DIM + c0 + c) * H_DIM + hg) * W_DIM + sg];
      } else {
        const int hg = h0 + (r - 12);
        if (sg >= 0 && sg < W_DIM)
          val = *(const float4*)&xg[((b * C_DIM + c0 + c) * H_DIM + hg) * W_DIM + sg];
      }
      v[i] = val;
    }

    __syncthreads();                    // previous chunk's LDS reads done
#pragma unroll
    for (int i = 0; i < 12; ++i) {
      const int qid = i * 256 + tid;
      const int q = qid % 6;
      const int c = (qid / 6) % CHUNK;
      const int r = qid / (6 * CHUNK);
      *(float4*)&lds[(r * CHUNK + c) * SPAD + q * 4] = v[i];
    }
    __syncthreads();

    // ---- A fragments: x row (LDS row 12+wv), logical s = MD+lm = col w0+lm.
    // _1k layout: lane holds A[m = lm][k = hi*4 + e] per k-half.
    s16x4 afr[2];
#pragma unroll
    for (int kh = 0; kh < 2; ++kh) {
      const int base = ((12 + wv) * CHUNK + kh * 16 + hi * 4) * SPAD + (MD + lm);
#pragma unroll
      for (int e = 0; e < 4; ++e) afr[kh][e] = bf16bits(lds[base + e * SPAD]);
    }

    // ---- 9 di x 2 N-tiles x 2 k-halves MFMA
#pragma unroll
    for (int di = 0; di < KD; ++di) {
      const int r = wv + di;            // y LDS row = global y row h+di-4
#pragma unroll
      for (int t = 0; t < 2; ++t) {
#pragma unroll
        for (int kh = 0; kh < 2; ++kh) {
          const int base = (r * CHUNK + kh * 16 + hi * 4) * SPAD + (t * 16 + lm);
          s16x4 bfr;
#pragma unroll
          for (int e = 0; e < 4; ++e) bfr[e] = bf16bits(lds[base + e * SPAD]);
          acc[di][t] = __builtin_amdgcn_mfma_f32_16x16x16bf16_1k(
              afr[kh], bfr, acc[di][t], 0, 0, 0);
        }
      }
    }
  }

  // ---- epilogue: band extraction + scale. D[m][n]: m = hi*4+reg, n = lm.
  const int h = h0 + wv;
  const float scale = 1.f / (float)C_DIM;
#pragma unroll
  for (int di = 0; di < KD; ++di) {
#pragma unroll
    for (int t = 0; t < 2; ++t) {
#pragma unroll
      for (int rg = 0; rg < 4; ++rg) {
        const int m = hi * 4 + rg;
        const int dj = t * 16 + lm - m;
        if (0 <= dj && dj <= 8) {
          outg[((b * (KD * KD) + di * KD + dj) * H_DIM + h) * W_DIM + w0 + m] =
              acc[di][t][rg] * scale;
        }
      }
    }
  }
}

extern "C" void kernel_launch(void* const* d_in, const int* in_sizes, int n_in,
                              void* d_out, int out_size, void* d_ws, size_t ws_size,
                              hipStream_t stream) {
  const float* x = (const float*)d_in[0];
  const float* y = (const float*)d_in[1];
  float* out = (float*)d_out;             // fp32 output
  (void)in_sizes; (void)n_in; (void)d_ws; (void)ws_size; (void)out_size;

  const int grid = 8 * HQ * WTILES;       // 8 * 24 * 12 = 2304 blocks
  corr_mfma<<<dim3(grid), dim3(256), 0, stream>>>(x, y, out);
}

// Round 2
// 140.289 us; speedup vs baseline: 1.7953x; 1.7953x over previous
//
#include <hip/hip_runtime.h>
#include <hip/hip_bf16.h>
#include <stdint.h>

// Correlation (FlowNet), md=4: out[b, di*9+dj, h, w] = sum_c x[b,c,h,w]*yp[b,c,h+di-4,w+dj-4] / 256
// R1: 8-wave blocks (HR=8), bf16 tr-subtiled LDS ([4c][16s] subtiles, 160B stride),
// ds_read_b64_tr_b16 fragment reads, 16x16x16 bf16 MFMA, batch-per-XCD swizzle.

using f32x4 = __attribute__((ext_vector_type(4))) float;
using s16x4 = __attribute__((ext_vector_type(4))) short;
using u16x4 = __attribute__((ext_vector_type(4))) unsigned short;

#define C_DIM 256
#define H_DIM 96
#define W_DIM 192
#define HWSZ  (H_DIM * W_DIM)
#define MD 4
#define KD 9
#define CHUNK 32
#define HR 8
#define NTHR 512
#define WTILES 12          // 192/16
#define HQ 12              // 96/8
#define SUB_B 160          // [4c][16s] bf16 subtile = 128B, padded to 160B (bank spread)
#define YROW_B (16 * SUB_B)   // 2 t * 8 cg subtiles = 2560B per y row
#define XROW_B (8 * SUB_B)    // t=0 only
#define XBASE  (16 * YROW_B)  // 40960
#define LDS_BYTES (XBASE + 8 * XROW_B)   // 51200

static __device__ __forceinline__ unsigned short bf16b(float f) {
  __bf16 h = (__bf16)f;                   // RNE
  unsigned short s; __builtin_memcpy(&s, &h, 2); return s;
}

// per-lane: reads column (addr&127)/8 of the [4c][16s] bf16 subtile containing addr
static __device__ __forceinline__ s16x4 tr16(uint32_t addr) {
  s16x4 d;
  asm volatile("ds_read_b64_tr_b16 %0, %1" : "=v"(d) : "v"(addr));
  return d;
}

__global__ __launch_bounds__(NTHR, 4)
void corr_mfma(const float* __restrict__ xg, const float* __restrict__ yg,
               float* __restrict__ outg) {
  __shared__ __align__(16) char smem[LDS_BYTES];

  const int bid = blockIdx.x;             // 1152 = 8 * 144
  const int b   = bid & 7;                // batch == XCD (round-robin dispatch)
  const int rem = bid >> 3;               // 0..143, hq fastest -> h-halo L2 reuse
  const int wt  = rem / HQ;
  const int hq  = rem - wt * HQ;
  const int w0  = wt * 16;
  const int h0  = hq * HR;

  const int tid  = threadIdx.x;
  const int lane = tid & 63;
  const int wv   = tid >> 6;              // wave id 0..7 -> output row h0+wv
  const int hi   = lane >> 4;
  const int lm   = lane & 15;

  const uint32_t sbase = (uint32_t)(uintptr_t)&smem[0];  // LDS aperture is 4GB-aligned

  // ---- staging decode, hoisted. i<6: y quads (16 rows x 32c x 6q); i 6,7: x (8 x 32c x 4q)
  uint32_t goffY[6], loffY[6], goffX[2], loffX[2];
  uint32_t vmaskY = 0;
#pragma unroll
  for (int i = 0; i < 6; ++i) {
    const int qid = i * NTHR + tid;
    const int q = qid % 6;
    const int c = (qid / 6) & 31;
    const int r = qid / 192;              // y row 0..15 -> h0+r-4
    const int hg = h0 + r - MD;
    const int sg = w0 - MD + 4 * q;       // 4-aligned: OOB is whole-quad
    const bool ok = (hg >= 0) && (hg < H_DIM) && (sg >= 0) && (sg < W_DIM);
    if (ok) vmaskY |= (1u << i);
    goffY[i] = ok ? (uint32_t)(((b * C_DIM + c) * H_DIM + hg) * W_DIM + sg) : 0u;
    const int s = 4 * q;                  // local s 0..20
    loffY[i] = r * YROW_B + (s >> 4) * (8 * SUB_B) + (c >> 2) * SUB_B
             + (c & 3) * 32 + (s & 15) * 2;
  }
#pragma unroll
  for (int i = 0; i < 2; ++i) {
    const int qid = i * NTHR + tid;
    const int q = qid & 3;                // x staged without w-halo: s = w-w0
    const int c = (qid >> 2) & 31;
    const int r = qid >> 7;               // 0..7 -> h0+r
    goffX[i] = (uint32_t)(((b * C_DIM + c) * H_DIM + (h0 + r)) * W_DIM + (w0 + 4 * q));
    loffX[i] = XBASE + r * XROW_B + (c >> 2) * SUB_B + (c & 3) * 32 + q * 8;
  }

  f32x4 acc[KD][2];
#pragma unroll
  for (int di = 0; di < KD; ++di) {
    acc[di][0] = f32x4{0.f, 0.f, 0.f, 0.f};
    acc[di][1] = f32x4{0.f, 0.f, 0.f, 0.f};
  }

  // fragment base addresses: subtile cg = kh*4+hi holds channels kh*16+hi*4..+3
  const uint32_t abase = sbase + XBASE + wv * XROW_B + hi * SUB_B + lm * 8;
  const uint32_t bbase = sbase + wv * YROW_B + hi * SUB_B + lm * 8;

  for (int c0 = 0; c0 < C_DIM; c0 += CHUNK) {
    // ---- global loads + convert (before barrier: overlaps other waves' compute)
    u16x4 wbuf[8];
#pragma unroll
    for (int i = 0; i < 6; ++i) {
      float4 v = make_float4(0.f, 0.f, 0.f, 0.f);
      if (vmaskY & (1u << i)) v = *(const float4*)(yg + goffY[i] + (uint32_t)c0 * HWSZ);
      wbuf[i] = u16x4{bf16b(v.x), bf16b(v.y), bf16b(v.z), bf16b(v.w)};
    }
#pragma unroll
    for (int i = 0; i < 2; ++i) {
      float4 v = *(const float4*)(xg + goffX[i] + (uint32_t)c0 * HWSZ);
      wbuf[6 + i] = u16x4{bf16b(v.x), bf16b(v.y), bf16b(v.z), bf16b(v.w)};
    }

    __syncthreads();                      // prior chunk's tr reads all drained (lgkmcnt(0) below)
#pragma unroll
    for (int i = 0; i < 6; ++i) *(u16x4*)(smem + loffY[i]) = wbuf[i];
#pragma unroll
    for (int i = 0; i < 2; ++i) *(u16x4*)(smem + loffX[i]) = wbuf[6 + i];
    __syncthreads();

    // ---- compute: A frags + one-di-ahead pipelined B tr reads
    s16x4 afr0 = tr16(abase);
    s16x4 afr1 = tr16(abase + 4 * SUB_B);
    s16x4 bc0 = tr16(bbase);
    s16x4 bc1 = tr16(bbase + 4 * SUB_B);
    s16x4 bc2 = tr16(bbase + 8 * SUB_B);
    s16x4 bc3 = tr16(bbase + 12 * SUB_B);
#pragma unroll
    for (int di = 0; di < KD; ++di) {
      s16x4 bn0, bn1, bn2, bn3;
      if (di < 8) {
        const uint32_t bb = bbase + (uint32_t)(di + 1) * YROW_B;  // y row wv+di+1
        bn0 = tr16(bb);
        bn1 = tr16(bb + 4 * SUB_B);
        bn2 = tr16(bb + 8 * SUB_B);
        bn3 = tr16(bb + 12 * SUB_B);
        asm volatile("s_waitcnt lgkmcnt(4)" ::: "memory");  // cur frags (+A) done
      } else {
        asm volatile("s_waitcnt lgkmcnt(0)" ::: "memory");
      }
      __builtin_amdgcn_sched_barrier(0);  // rule #18: don't hoist MFMA past waitcnt
      acc[di][0] = __builtin_amdgcn_mfma_f32_16x16x16bf16_1k(afr0, bc0, acc[di][0], 0, 0, 0);
      acc[di][0] = __builtin_amdgcn_mfma_f32_16x16x16bf16_1k(afr1, bc1, acc[di][0], 0, 0, 0);
      acc[di][1] = __builtin_amdgcn_mfma_f32_16x16x16bf16_1k(afr0, bc2, acc[di][1], 0, 0, 0);
      acc[di][1] = __builtin_amdgcn_mfma_f32_16x16x16bf16_1k(afr1, bc3, acc[di][1], 0, 0, 0);
      if (di < 8) { bc0 = bn0; bc1 = bn1; bc2 = bn2; bc3 = bn3; }
    }
  }

  // ---- epilogue: D[m][n]: n=lm, m=hi*4+rg (verified R0). dj = t*16 + lm - m.
  const int h = h0 + wv;
  const float scale = 1.f / 256.f;
#pragma unroll
  for (int di = 0; di < KD; ++di) {
#pragma unroll
    for (int t = 0; t < 2; ++t) {
#pragma unroll
      for (int rg = 0; rg < 4; ++rg) {
        const int m = hi * 4 + rg;
        const int dj = t * 16 + lm - m;
        if (0 <= dj && dj <= 8) {
          outg[((b * (KD * KD) + di * KD + dj) * H_DIM + h) * W_DIM + w0 + m] =
              acc[di][t][rg] * scale;
        }
      }
    }
  }
}

extern "C" void kernel_launch(void* const* d_in, const int* in_sizes, int n_in,
                              void* d_out, int out_size, void* d_ws, size_t ws_size,
                              hipStream_t stream) {
  const float* x = (const float*)d_in[0];
  const float* y = (const float*)d_in[1];
  float* out = (float*)d_out;
  (void)in_sizes; (void)n_in; (void)d_ws; (void)ws_size; (void)out_size;

  const int grid = 8 * HQ * WTILES;       // 1152 blocks, 512 threads
  corr_mfma<<<dim3(grid), dim3(NTHR), 0, stream>>>(x, y, out);
}